// Round 1
// baseline (622.725 us; speedup 1.0000x reference)
//
#include <hip/hip_runtime.h>

#define NR    32768
#define NOBJ  16
#define NS    32
#define NB    64
#define WIDTH 576          // NB + NOBJ*NS
#define MISSV 1e10f

// ---- pinned fp32 ops: identical rounding everywhere ----
__device__ __forceinline__ float fmulr(float a, float b){ return __fmul_rn(a,b); }
__device__ __forceinline__ float faddr(float a, float b){ return __fadd_rn(a,b); }
__device__ __forceinline__ float fsubr(float a, float b){ return __fsub_rn(a,b); }
__device__ __forceinline__ float fdvr (float a, float b){ return __fdiv_rn(a,b); }

struct RayObj {
  float oo[3];   // ray origin in object frame
  float dd[3];   // normalized ray dir in object frame
  float t_in, dt;
  float dn;      // |d_w @ M3x3|  (object-t -> world-z divisor)
  bool  hit;
};

// Shared by both roles so hit/t_in/dt are bit-identical across them.
__device__ __forceinline__ void ray_obj_setup(
    const float* __restrict__ origins, const float* __restrict__ dirs,
    const float* __restrict__ trafos,  const float* __restrict__ scales,
    int m, int n, RayObj& R)
{
  const float o0 = origins[3*n+0], o1 = origins[3*n+1], o2 = origins[3*n+2];
  const float r0 = dirs[3*n+0],    r1 = dirs[3*n+1],    r2 = dirs[3*n+2];
  const float nn = __fsqrt_rn(faddr(faddr(fmulr(r0,r0), fmulr(r1,r1)), fmulr(r2,r2)));
  const float w0 = fdvr(r0,nn), w1 = fdvr(r1,nn), w2 = fdvr(r2,nn);

  const float* T = trafos + 16*m;
  const float* S = scales + 16*m;
  const float s0 = S[0], s1 = S[5], s2 = S[10];
  const float pm00 = fmulr(T[0],  s0), pm01 = fmulr(T[1],  s1), pm02 = fmulr(T[2],  s2);
  const float pm10 = fmulr(T[4],  s0), pm11 = fmulr(T[5],  s1), pm12 = fmulr(T[6],  s2);
  const float pm20 = fmulr(T[8],  s0), pm21 = fmulr(T[9],  s1), pm22 = fmulr(T[10], s2);
  const float tm0  = fmulr(T[12], s0), tm1  = fmulr(T[13], s1), tm2  = fmulr(T[14], s2);

  const float oo0 = faddr(faddr(faddr(fmulr(o0,pm00), fmulr(o1,pm10)), fmulr(o2,pm20)), tm0);
  const float oo1 = faddr(faddr(faddr(fmulr(o0,pm01), fmulr(o1,pm11)), fmulr(o2,pm21)), tm1);
  const float oo2 = faddr(faddr(faddr(fmulr(o0,pm02), fmulr(o1,pm12)), fmulr(o2,pm22)), tm2);
  const float du0 = faddr(faddr(fmulr(w0,pm00), fmulr(w1,pm10)), fmulr(w2,pm20));
  const float du1 = faddr(faddr(fmulr(w0,pm01), fmulr(w1,pm11)), fmulr(w2,pm21));
  const float du2 = faddr(faddr(fmulr(w0,pm02), fmulr(w1,pm12)), fmulr(w2,pm22));
  const float dn  = __fsqrt_rn(faddr(faddr(fmulr(du0,du0), fmulr(du1,du1)), fmulr(du2,du2)));
  const float dd0 = fdvr(du0,dn), dd1 = fdvr(du1,dn), dd2 = fdvr(du2,dn);

  const float i0 = fdvr(1.0f, dd0), i1 = fdvr(1.0f, dd1), i2 = fdvr(1.0f, dd2);
  const float a0 = fmulr(fsubr(-1.0f, oo0), i0), b0 = fmulr(fsubr(1.0f, oo0), i0);
  const float a1 = fmulr(fsubr(-1.0f, oo1), i1), b1 = fmulr(fsubr(1.0f, oo1), i1);
  const float a2 = fmulr(fsubr(-1.0f, oo2), i2), b2 = fmulr(fsubr(1.0f, oo2), i2);
  const float tmn = fmaxf(fmaxf(fminf(a0,b0), fminf(a1,b1)), fminf(a2,b2));
  const float tmx = fminf(fminf(fmaxf(a0,b0), fmaxf(a1,b1)), fmaxf(a2,b2));

  R.hit  = (tmx > tmn) && (tmx > 0.0f);
  R.t_in = fmaxf(tmn, 0.0f);
  R.dt   = fsubr(tmx, R.t_in);
  R.dn   = dn;
  R.oo[0]=oo0; R.oo[1]=oo1; R.oo[2]=oo2;
  R.dd[0]=dd0; R.dd[1]=dd1; R.dd[2]=dd2;
}

// count of elements in run (A2,B2) ordered before `key` (tie -> run precedes iff `tie`)
// Pure-register: run key at index c is RECOMPUTED as faddr(A2, fmulr(B2, (float)c)),
// bit-identical to how phase B generated the stored keys (same pinned ops, same A/B).
__device__ __forceinline__ int count_run_reg(float A2, float B2, float IB2,
                                             float key, bool tie)
{
  if (B2 <= 0.0f) {  // degenerate run: all 32 keys equal A2
    return (A2 < key || (A2 == key && tie)) ? NS : 0;
  }
  float g = floorf(fmulr(fsubr(key, A2), IB2));
  g = fminf(33.0f, fmaxf(-1.0f, g));
  int c = (int)g + 1;
  c = c < 0 ? 0 : (c > NS ? NS : c);
  while (c > 0) {
    const float v = faddr(A2, fmulr(B2, (float)(c-1)));
    if (v < key || (v == key && tie)) break;
    --c;
  }
  while (c < NS) {
    const float v = faddr(A2, fmulr(B2, (float)c));
    if (v < key || (v == key && tie)) ++c; else break;
  }
  return c;
}

struct PtsS  { float ld[64][8]; };
struct SortS {
  float sBase[4][NB];                       // base keys only (binary-search target)
  float sA[4][NOBJ], sB[4][NOBJ], sIB[4][NOBJ];
  float sL[4][WIDTH], sN[4][WIDTH];
};
union __align__(16) Smem { PtsS p; SortS s; };   // ~19.8 KB (was 28.6) -> more blocks/CU

// ============ Fused kernel: even blocks write pts/dirs, odd blocks rank-sort ============
// Role interleave => every CU co-resides write-bound and VALU-bound blocks (m114 overlap).
__global__ __launch_bounds__(256) void k_fused(
    const float* __restrict__ origins, const float* __restrict__ dirs,
    const float* __restrict__ lengths,
    const float* __restrict__ trafos,  const float* __restrict__ scales,
    float* __restrict__ outL, float* __restrict__ outN, float* __restrict__ outM,
    float* __restrict__ outP, float* __restrict__ outD)
{
  __shared__ Smem U;
  const int tid  = threadIdx.x;
  const int role = blockIdx.x & 1;
  const int bid  = blockIdx.x >> 1;

  if (role == 0) {
    // ---------------- pts/dirs writer (unchanged; BW-bound) ----------------
    const int m   = bid >> 9;          // 16 objects
    const int n0  = (bid & 511) << 6;  // 512 chunks of 64 rays
    if (tid < 64) {
      RayObj R;
      ray_obj_setup(origins, dirs, trafos, scales, m, n0 + tid, R);
      const bool h = R.hit;
      U.p.ld[tid][0] = h ? R.oo[0] : 0.0f;
      U.p.ld[tid][1] = h ? R.oo[1] : 0.0f;
      U.p.ld[tid][2] = h ? R.oo[2] : 0.0f;
      U.p.ld[tid][3] = h ? R.dd[0] : 0.0f;
      U.p.ld[tid][4] = h ? R.dd[1] : 0.0f;
      U.p.ld[tid][5] = h ? R.t_in  : 0.0f;
      U.p.ld[tid][6] = h ? R.dt    : 0.0f;
      U.p.ld[tid][7] = h ? R.dd[2] : 0.0f;
    }
    __syncthreads();   // cross-wave: wave 0 produced, all 4 waves consume
    const size_t base = (size_t)(m * NR + n0) * 96;
    float4* P4 = (float4*)(outP + base);
    float4* D4 = (float4*)(outD + base);
    #pragma unroll
    for (int it = 0; it < 6; ++it) {
      const int f   = tid + (it << 8);   // float4 index, lane-consecutive -> coalesced
      const int rr  = f / 24;            // ray within block (24 float4 per ray)
      const int off = (f - rr * 24) * 4; // float offset within ray region [0,96)
      const float oox = U.p.ld[rr][0], ooy = U.p.ld[rr][1], ooz = U.p.ld[rr][2];
      const float ddx = U.p.ld[rr][3], ddy = U.p.ld[rr][4], ddz = U.p.ld[rr][7];
      const float ti  = U.p.ld[rr][5], dtt = U.p.ld[rr][6];
      float4 p, d;
      float* pp = (float*)&p; float* dv = (float*)&d;
      #pragma unroll
      for (int i = 0; i < 4; ++i) {
        const int idx = off + i;
        const int s   = idx / 3;
        const int c   = idx - s * 3;
        const float z  = ti + dtt * ((float)s * (1.0f/31.0f));
        const float oc = (c == 0) ? oox : ((c == 1) ? ooy : ooz);
        const float dc = (c == 0) ? ddx : ((c == 1) ? ddy : ddz);
        pp[i] = oc + dc * z;   // miss rays: all-zero params -> exact 0 output
        dv[i] = dc;
      }
      P4[f] = p;
      D4[f] = d;
    }
    return;
  }

  // ---------------- rank-sort (4 rays per block, one wave per ray) ----------------
  // ALL shared state below is indexed [wv] -> strictly per-wave. No cross-wave
  // sharing => no s_barrier needed anywhere; wave-internal LDS is in-order on CDNA.
  // asm memory fences only pin compiler ordering at the former barrier points.
  const int wv   = tid >> 6;
  const int lane = tid & 63;
  const int n    = bid * 4 + wv;

  // phase A: lanes 0..15 compute per-object key-line params.
  // Exact identity: world z of object-t sample = t/dn (round-trip through o2w collapses).
  bool myhit = false;
  if (lane < NOBJ) {
    RayObj R;
    ray_obj_setup(origins, dirs, trafos, scales, lane, n, R);
    myhit = R.hit;
    float myA = MISSV, myB = -1.0f, myIB = 0.0f;
    if (R.hit) {
      const double invdn = 1.0 / (double)R.dn;
      myA = (float)((double)R.t_in * invdn);
      myB = (float)(((double)R.dt * invdn) * (1.0 / 31.0));
      if (!(myB > 0.0f)) myB = 0.0f;
      myIB = (myB > 0.0f) ? (1.0f / myB) : 0.0f;
    }
    U.s.sA[wv][lane]  = myA;
    U.s.sB[wv][lane]  = R.hit ? myB : -1.0f;       // B<0 encodes miss
    U.s.sIB[wv][lane] = myIB;
  }
  const unsigned hm = (unsigned)(__ballot(myhit) & 0xFFFFull);  // hit mask, wave-uniform
  const int H = __popc(hm);
  asm volatile("" ::: "memory");

  // phase B: generate the 9 keys this lane owns (base + 8 run elements), regs only
  float kr[9];
  kr[0] = lengths[n * NB + lane];
  U.s.sBase[wv][lane] = kr[0];
  #pragma unroll
  for (int k = 1; k < 9; ++k) {
    const int m0 = 2*(k-1) + (lane >> 5);
    const int s  = lane & 31;
    if ((hm >> m0) & 1u) {
      const float A_ = U.s.sA[wv][m0], B_ = U.s.sB[wv][m0];
      kr[k] = faddr(A_, fmulr(B_, (float)s));
    } else {
      kr[k] = MISSV;
    }
  }
  asm volatile("" ::: "memory");

  // phase C1: base-rank of each element (binary search over the 64 sorted base keys)
  const float* K = U.s.sBase[wv];
  int rnk[9];
  rnk[0] = lane;                                   // stable: base precedes all on ties
  #pragma unroll
  for (int k = 1; k < 9; ++k) {
    const int m = 2*(k-1) + (lane >> 5);
    const int s = lane & 31;
    if ((hm >> m) & 1u) {
      int c = 0;                                   // upper_bound over sorted base lengths
      const float key = kr[k];
      #pragma unroll
      for (int st = 64; st >= 1; st >>= 1) {
        const int t2 = c + st;
        if (t2 <= NB && K[t2-1] <= key) c = t2;
      }
      rnk[k] = s + c;
    } else {
      const int MB = __popc((~hm) & ((1u << m) - 1u) & 0xFFFFu);
      rnk[k] = NB + NS*H + NS*MB + s;              // closed-form tail rank
    }
  }

  // phase C2: cross-run counts. Runs outer (uniform loop, A/B/IB loaded ONCE per run),
  // all 9 elements inner (independent -> ILP). Zero LDS key reads in here.
  unsigned mm = hm;
  while (mm) {
    const int m2 = __ffs(mm) - 1; mm &= mm - 1;
    const float A2  = U.s.sA[wv][m2];
    const float B2  = U.s.sB[wv][m2];
    const float IB2 = U.s.sIB[wv][m2];
    rnk[0] += count_run_reg(A2, B2, IB2, kr[0], false);
    #pragma unroll
    for (int k = 1; k < 9; ++k) {
      const int m = 2*(k-1) + (lane >> 5);
      if (((hm >> m) & 1u) && m != m2)
        rnk[k] += count_run_reg(A2, B2, IB2, kr[k], m2 < m);
    }
  }

  // phase C3: scatter (key,node) into LDS at exact rank (permutation -> no collisions)
  U.s.sL[wv][rnk[0]] = kr[0];
  U.s.sN[wv][rnk[0]] = -1.0f;
  #pragma unroll
  for (int k = 1; k < 9; ++k) {
    const int m = 2*(k-1) + (lane >> 5);
    const bool h = (hm >> m) & 1u;
    U.s.sL[wv][rnk[k]] = kr[k];                    // miss elements carry MISSV already
    U.s.sN[wv][rnk[k]] = h ? (float)m : -1.0f;
  }
  asm volatile("" ::: "memory");

  // coalesced copy-out: 144 float4 per array per ray; mask derived from node
  float4* pL = (float4*)(outL + (size_t)n * WIDTH);
  float4* pN = (float4*)(outN + (size_t)n * WIDTH);
  float4* pM = (float4*)(outM + (size_t)n * WIDTH);
  const float4* qL = (const float4*)U.s.sL[wv];
  const float4* qN = (const float4*)U.s.sN[wv];
  for (int i = lane; i < WIDTH/4; i += 64) pL[i] = qL[i];
  for (int i = lane; i < WIDTH/4; i += 64) {
    const float4 nv = qN[i];
    float4 mv;
    mv.x = nv.x >= 0.0f ? 1.0f : 0.0f;
    mv.y = nv.y >= 0.0f ? 1.0f : 0.0f;
    mv.z = nv.z >= 0.0f ? 1.0f : 0.0f;
    mv.w = nv.w >= 0.0f ? 1.0f : 0.0f;
    pN[i] = nv;
    pM[i] = mv;
  }
}

extern "C" void kernel_launch(void* const* d_in, const int* in_sizes, int n_in,
                              void* d_out, int out_size, void* d_ws, size_t ws_size,
                              hipStream_t stream)
{
  (void)in_sizes; (void)n_in; (void)out_size; (void)d_ws; (void)ws_size;
  const float* origins = (const float*)d_in[0];
  const float* dirs    = (const float*)d_in[1];
  const float* lengths = (const float*)d_in[2];
  const float* trafos  = (const float*)d_in[3];
  // d_in[4] = rots_w2o: its 3x3 equals trafos' 3x3 (dir transform) -> unused
  const float* scales  = (const float*)d_in[5];

  float* out  = (float*)d_out;
  float* outL = out;
  float* outN = out + (size_t)NR * WIDTH;
  float* outM = out + (size_t)2 * NR * WIDTH;
  float* outP = out + (size_t)3 * NR * WIDTH;
  float* outD = outP + (size_t)NOBJ * NR * NS * 3;

  // even blocks: 8192 pts-writer tiles; odd blocks: 8192 sort blocks (4 rays each)
  hipLaunchKernelGGL(k_fused, dim3(16384), dim3(256), 0, stream,
                     origins, dirs, lengths, trafos, scales,
                     outL, outN, outM, outP, outD);
}